// Round 2
// baseline (1954.882 us; speedup 1.0000x reference)
//
#include <hip/hip_runtime.h>

#define DIM   1536
#define NQKV  4608
#define NH    24
#define HD    64
#define BATCH 4
#define SEQ   4096
#define ROWS  16384   // BATCH*SEQ

typedef _Float16 f16x8 __attribute__((ext_vector_type(8)));
typedef float    f32x4 __attribute__((ext_vector_type(4)));

__device__ __forceinline__ void gload_lds16(const void* g, void* l) {
  __builtin_amdgcn_global_load_lds(
      (const __attribute__((address_space(1))) unsigned int*)g,
      (__attribute__((address_space(3))) unsigned int*)l, 16, 0, 0);
}
__device__ __forceinline__ float fexp2(float x) {
#if __has_builtin(__builtin_amdgcn_exp2f)
  return __builtin_amdgcn_exp2f(x);
#else
  return exp2f(x);
#endif
}

// ---------------- kernel 0: X fp32 -> fp16 --------------------------------
__global__ __launch_bounds__(256) void convert_x(const float* __restrict__ X,
                                                 _Float16* __restrict__ Xh) {
  const int i = (blockIdx.x * 256 + threadIdx.x) * 8;
  float4 a = *(const float4*)(X + i);
  float4 b = *(const float4*)(X + i + 4);
  f16x8 h;
  h[0] = (_Float16)a.x; h[1] = (_Float16)a.y; h[2] = (_Float16)a.z; h[3] = (_Float16)a.w;
  h[4] = (_Float16)b.x; h[5] = (_Float16)b.y; h[6] = (_Float16)b.z; h[7] = (_Float16)b.w;
  *(f16x8*)(Xh + i) = h;
}

// ---------------- kernel 1: W (K x N) fp32 -> Wt (N x K) fp16 -------------
__global__ __launch_bounds__(256) void transpose_w(const float* __restrict__ W,
                                                   _Float16* __restrict__ Wt) {
  __shared__ float tile[32][33];
  const int tx = threadIdx.x, ty = threadIdx.y;        // 32 x 8
  const int k0 = blockIdx.y * 32, n0 = blockIdx.x * 32;
  #pragma unroll
  for (int i = 0; i < 32; i += 8)
    tile[ty + i][tx] = W[(size_t)(k0 + ty + i) * NQKV + n0 + tx];
  __syncthreads();
  #pragma unroll
  for (int i = 0; i < 32; i += 8)
    Wt[(size_t)(n0 + ty + i) * DIM + k0 + tx] = (_Float16)tile[tx][ty + i];
}

// ---------------- kernel 2: QKV = Xh @ Wt^T + b  (fp16 MFMA) --------------
__global__ __launch_bounds__(256) void qkv_gemm(const _Float16* __restrict__ Xh,
                                                const _Float16* __restrict__ Wt,
                                                const float* __restrict__ Bias,
                                                _Float16* __restrict__ QKV) {
  __shared__ _Float16 As[128 * 64];
  __shared__ _Float16 Bs[128 * 64];
  const int w    = threadIdx.x >> 6;
  const int lane = threadIdx.x & 63;
  const int lr   = lane >> 3, lc = lane & 7;
  const int quad = lane >> 4, l15 = lane & 15;
  const int m0 = blockIdx.y * 128;
  const int n0 = blockIdx.x * 128;
  const int waveR = (w >> 1) * 64;
  const int waveC = (w & 1) * 64;

  f32x4 acc[4][4];
  #pragma unroll
  for (int i = 0; i < 4; i++)
    #pragma unroll
    for (int j = 0; j < 4; j++) acc[i][j] = (f32x4){0.f, 0.f, 0.f, 0.f};

  for (int kt = 0; kt < DIM / 64; ++kt) {
    const int k0 = kt * 64;
    #pragma unroll
    for (int i = 0; i < 4; ++i) {
      const int rr = w * 32 + i * 8;
      gload_lds16(Xh + (size_t)(m0 + rr + lr) * DIM + k0 + lc * 8, &As[rr * 64]);
      gload_lds16(Wt + (size_t)(n0 + rr + lr) * DIM + k0 + lc * 8, &Bs[rr * 64]);
    }
    __syncthreads();
    #pragma unroll
    for (int ks = 0; ks < 2; ++ks) {
      f16x8 aF[4], bF[4];
      #pragma unroll
      for (int t = 0; t < 4; t++)
        aF[t] = *(const f16x8*)&As[(waveR + t * 16 + l15) * 64 + ks * 32 + quad * 8];
      #pragma unroll
      for (int t = 0; t < 4; t++)
        bF[t] = *(const f16x8*)&Bs[(waveC + t * 16 + l15) * 64 + ks * 32 + quad * 8];
      #pragma unroll
      for (int mt = 0; mt < 4; mt++)
        #pragma unroll
        for (int nt = 0; nt < 4; nt++)
          acc[mt][nt] = __builtin_amdgcn_mfma_f32_16x16x32_f16(aF[mt], bF[nt], acc[mt][nt], 0, 0, 0);
    }
    __syncthreads();
  }
  #pragma unroll
  for (int nt = 0; nt < 4; nt++) {
    const int n = n0 + waveC + nt * 16 + l15;
    const float bias = Bias[n];
    #pragma unroll
    for (int mt = 0; mt < 4; mt++) {
      const int mBase = m0 + waveR + mt * 16 + quad * 4;
      #pragma unroll
      for (int r = 0; r < 4; r++)
        QKV[(size_t)(mBase + r) * NQKV + n] = (_Float16)(acc[mt][nt][r] + bias);
    }
  }
}

// ---------------- kernel 3: RMSNorm(q,k) + RoPE, in place -----------------
__global__ __launch_bounds__(256) void rms_rope(_Float16* __restrict__ QKV,
                                                const float* __restrict__ Cos,
                                                const float* __restrict__ Sin) {
  const int gw   = blockIdx.x * 4 + (threadIdx.x >> 6);
  const int lane = threadIdx.x & 63;
  const int row  = gw / NH;
  const int h    = gw - row * NH;
  const int s    = row & (SEQ - 1);

  _Float16* p = QKV + (size_t)row * NQKV + h * HD;
  float q = (float)p[lane];
  float k = (float)p[DIM + lane];

  float sq = q * q, sk = k * k;
  #pragma unroll
  for (int off = 1; off < 64; off <<= 1) {
    sq += __shfl_xor(sq, off);
    sk += __shfl_xor(sk, off);
  }
  q *= rsqrtf(sq * (1.f / 64.f) + 1e-6f);
  k *= rsqrtf(sk * (1.f / 64.f) + 1e-6f);

  const float c  = Cos[s * HD + lane];
  const float si = Sin[s * HD + lane];
  const float qp = __shfl_xor(q, 1);
  const float kp = __shfl_xor(k, 1);
  float oq, ok;
  if (lane & 1) { oq = q * c + qp * si; ok = k * c + kp * si; }
  else          { oq = q * c - qp * si; ok = k * c - kp * si; }

  p[lane]       = (_Float16)oq;
  p[DIM + lane] = (_Float16)ok;
}

// ---------------- kernel 4: flash attention (fp16 MFMA, fp32 out) ---------
#define LSTR 72
__global__ __launch_bounds__(256) void flash_attn(const _Float16* __restrict__ QKV,
                                                  float* __restrict__ Out) {
  __shared__ __align__(16) _Float16 sm[3 * 64 * LSTR + 4 * 16 * LSTR];
  _Float16* Qs  = sm;
  _Float16* Ks  = sm + 64 * LSTR;
  _Float16* Vts = sm + 2 * 64 * LSTR;
  const int w    = threadIdx.x >> 6;
  _Float16* Ps = sm + 3 * 64 * LSTR + w * 16 * LSTR;
  const int lane = threadIdx.x & 63;
  const int quad = lane >> 4, l15 = lane & 15;
  const int bh = blockIdx.y;
  const int qt = blockIdx.x;
  const int b  = bh / NH;
  const int h  = bh - b * NH;
  const size_t rowb = (size_t)b * SEQ * NQKV + (size_t)h * HD;  // + s*NQKV selects token

  // stage Q tile (64 x 64) from strided QKV rows
  #pragma unroll
  for (int i = 0; i < 2; i++) {
    const int chunk = threadIdx.x + i * 256;
    const int r = chunk >> 3, c0 = (chunk & 7) * 8;
    *(uint4*)&Qs[r * LSTR + c0] =
        *(const uint4*)(QKV + rowb + (size_t)(qt * 64 + r) * NQKV + c0);
  }

  f32x4 o[4];
  #pragma unroll
  for (int t = 0; t < 4; t++) o[t] = (f32x4){0.f, 0.f, 0.f, 0.f};
  float mrow[4], lrow[4];
  #pragma unroll
  for (int r = 0; r < 4; r++) { mrow[r] = -1e30f; lrow[r] = 0.f; }

  const float C = 0.125f * 1.44269504088896340736f;  // scale * log2(e)

  for (int kt = 0; kt < SEQ / 64; ++kt) {
    __syncthreads();
    // stage K tile
    #pragma unroll
    for (int i = 0; i < 2; i++) {
      const int chunk = threadIdx.x + i * 256;
      const int r = chunk >> 3, c0 = (chunk & 7) * 8;
      *(uint4*)&Ks[r * LSTR + c0] =
          *(const uint4*)(QKV + rowb + (size_t)(kt * 64 + r) * NQKV + DIM + c0);
    }
    // stage V tile transposed: Vts[d][key]
    #pragma unroll
    for (int i = 0; i < 2; i++) {
      const int c0 = w * 16 + i * 8;
      union { uint4 v; _Float16 u[8]; } d;
      d.v = *(const uint4*)(QKV + rowb + (size_t)(kt * 64 + lane) * NQKV + 2 * DIM + c0);
      #pragma unroll
      for (int j = 0; j < 8; j++) Vts[(c0 + j) * LSTR + lane] = d.u[j];
    }
    __syncthreads();

    // S = Q K^T for this wave's 16 q-rows
    f32x4 sacc[4];
    #pragma unroll
    for (int t = 0; t < 4; t++) sacc[t] = (f32x4){0.f, 0.f, 0.f, 0.f};
    #pragma unroll
    for (int ks = 0; ks < 2; ks++) {
      f16x8 aF = *(const f16x8*)&Qs[(w * 16 + l15) * LSTR + ks * 32 + quad * 8];
      #pragma unroll
      for (int t = 0; t < 4; t++) {
        f16x8 bF = *(const f16x8*)&Ks[(t * 16 + l15) * LSTR + ks * 32 + quad * 8];
        sacc[t] = __builtin_amdgcn_mfma_f32_16x16x32_f16(aF, bF, sacc[t], 0, 0, 0);
      }
    }

    // online softmax (log2 domain); C-layout rows = quad*4+r, cols = t*16+l15
    float x[4][4], rmax[4];
    #pragma unroll
    for (int r = 0; r < 4; r++) rmax[r] = -1e30f;
    #pragma unroll
    for (int t = 0; t < 4; t++)
      #pragma unroll
      for (int r = 0; r < 4; r++) {
        x[t][r] = sacc[t][r] * C;
        rmax[r] = fmaxf(rmax[r], x[t][r]);
      }
    #pragma unroll
    for (int off = 1; off < 16; off <<= 1)
      #pragma unroll
      for (int r = 0; r < 4; r++) rmax[r] = fmaxf(rmax[r], __shfl_xor(rmax[r], off));

    float alpha[4], rsum[4];
    #pragma unroll
    for (int r = 0; r < 4; r++) {
      const float mn = fmaxf(mrow[r], rmax[r]);
      alpha[r] = fexp2(mrow[r] - mn);
      mrow[r] = mn;
      rsum[r] = 0.f;
    }
    #pragma unroll
    for (int t = 0; t < 4; t++)
      #pragma unroll
      for (int r = 0; r < 4; r++) {
        const float pp = fexp2(x[t][r] - mrow[r]);
        const _Float16 ph = (_Float16)pp;
        Ps[(quad * 4 + r) * LSTR + t * 16 + l15] = ph;
        rsum[r] += (float)ph;   // sum the ROUNDED p -> exact renormalization
      }
    #pragma unroll
    for (int off = 1; off < 16; off <<= 1)
      #pragma unroll
      for (int r = 0; r < 4; r++) rsum[r] += __shfl_xor(rsum[r], off);
    #pragma unroll
    for (int r = 0; r < 4; r++) lrow[r] = lrow[r] * alpha[r] + rsum[r];
    #pragma unroll
    for (int t = 0; t < 4; t++)
      #pragma unroll
      for (int r = 0; r < 4; r++) o[t][r] *= alpha[r];

    // O += P V   (P re-read from per-wave LDS in A-operand layout)
    #pragma unroll
    for (int ks = 0; ks < 2; ks++) {
      f16x8 pF = *(const f16x8*)&Ps[l15 * LSTR + ks * 32 + quad * 8];
      #pragma unroll
      for (int t = 0; t < 4; t++) {
        f16x8 vF = *(const f16x8*)&Vts[(t * 16 + l15) * LSTR + ks * 32 + quad * 8];
        o[t] = __builtin_amdgcn_mfma_f32_16x16x32_f16(pF, vF, o[t], 0, 0, 0);
      }
    }
  }

  // epilogue: normalize, fp32 out (B, S, H*D)
  #pragma unroll
  for (int t = 0; t < 4; t++)
    #pragma unroll
    for (int r = 0; r < 4; r++) {
      const int srow = qt * 64 + w * 16 + quad * 4 + r;
      const int d = t * 16 + l15;
      Out[((size_t)(b * SEQ + srow)) * DIM + h * HD + d] = o[t][r] / lrow[r];
    }
}

// ---------------- launch --------------------------------------------------
extern "C" void kernel_launch(void* const* d_in, const int* in_sizes, int n_in,
                              void* d_out, int out_size, void* d_ws, size_t ws_size,
                              hipStream_t stream) {
  const float* X    = (const float*)d_in[0];
  const float* Cos  = (const float*)d_in[1];
  const float* Sin  = (const float*)d_in[2];
  const float* W    = (const float*)d_in[3];
  const float* Bias = (const float*)d_in[4];
  float* Out = (float*)d_out;

  char* ws = (char*)d_ws;
  _Float16* Xh  = (_Float16*)(ws);                  // 16384x1536 fp16 = 50,331,648 B
  _Float16* Wt  = (_Float16*)(ws + 50331648);       // 4608x1536 fp16  = 14,155,776 B
  _Float16* QKV = (_Float16*)(ws + 64487424);       // 16384x4608 fp16 = 150,994,944 B  (end 215,482,368)

  convert_x  <<<dim3(ROWS * DIM / (8 * 256)), 256, 0, stream>>>(X, Xh);
  transpose_w<<<dim3(NQKV / 32, DIM / 32), dim3(32, 8), 0, stream>>>(W, Wt);
  qkv_gemm   <<<dim3(NQKV / 128, ROWS / 128), 256, 0, stream>>>(Xh, Wt, Bias, QKV);
  rms_rope   <<<dim3(ROWS * NH / 4), 256, 0, stream>>>(QKV, Cos, Sin);
  flash_attn <<<dim3(SEQ / 64, BATCH * NH), 256, 0, stream>>>(QKV, Out);
}

// Round 3
// 1275.677 us; speedup vs baseline: 1.5324x; 1.5324x over previous
//
#include <hip/hip_runtime.h>

#define DIM   1536
#define NQKV  4608
#define NH    24
#define HD    64
#define BATCH 4
#define SEQ   4096
#define ROWS  16384   // BATCH*SEQ

typedef _Float16 f16x8 __attribute__((ext_vector_type(8)));
typedef float    f32x4 __attribute__((ext_vector_type(4)));

__device__ __forceinline__ void gload_lds16(const void* g, void* l) {
  __builtin_amdgcn_global_load_lds(
      (const __attribute__((address_space(1))) unsigned int*)g,
      (__attribute__((address_space(3))) unsigned int*)l, 16, 0, 0);
}
__device__ __forceinline__ float fexp2(float x) {
#if __has_builtin(__builtin_amdgcn_exp2f)
  return __builtin_amdgcn_exp2f(x);
#else
  return exp2f(x);
#endif
}

// scale * log2(e), folded into q inside rms_rope
#define QSCALE 0.18033688011112042f

// ---------------- kernel 0: X fp32 -> fp16 --------------------------------
__global__ __launch_bounds__(256) void convert_x(const float* __restrict__ X,
                                                 _Float16* __restrict__ Xh) {
  const int i = (blockIdx.x * 256 + threadIdx.x) * 8;
  float4 a = *(const float4*)(X + i);
  float4 b = *(const float4*)(X + i + 4);
  f16x8 h;
  h[0] = (_Float16)a.x; h[1] = (_Float16)a.y; h[2] = (_Float16)a.z; h[3] = (_Float16)a.w;
  h[4] = (_Float16)b.x; h[5] = (_Float16)b.y; h[6] = (_Float16)b.z; h[7] = (_Float16)b.w;
  *(f16x8*)(Xh + i) = h;
}

// ---------------- kernel 1: W (K x N) fp32 -> Wt (N x K) fp16 -------------
__global__ __launch_bounds__(256) void transpose_w(const float* __restrict__ W,
                                                   _Float16* __restrict__ Wt) {
  __shared__ float tile[32][33];
  const int tx = threadIdx.x, ty = threadIdx.y;        // 32 x 8
  const int k0 = blockIdx.y * 32, n0 = blockIdx.x * 32;
  #pragma unroll
  for (int i = 0; i < 32; i += 8)
    tile[ty + i][tx] = W[(size_t)(k0 + ty + i) * NQKV + n0 + tx];
  __syncthreads();
  #pragma unroll
  for (int i = 0; i < 32; i += 8)
    Wt[(size_t)(n0 + ty + i) * DIM + k0 + tx] = (_Float16)tile[tx][ty + i];
}

// ---------------- kernel 2: QKV = Xh @ Wt^T + b  (fp16 MFMA) --------------
__global__ __launch_bounds__(256) void qkv_gemm(const _Float16* __restrict__ Xh,
                                                const _Float16* __restrict__ Wt,
                                                const float* __restrict__ Bias,
                                                _Float16* __restrict__ QKV) {
  __shared__ _Float16 As[128 * 64];
  __shared__ _Float16 Bs[128 * 64];
  const int w    = threadIdx.x >> 6;
  const int lane = threadIdx.x & 63;
  const int lr   = lane >> 3, lc = lane & 7;
  const int quad = lane >> 4, l15 = lane & 15;
  const int m0 = blockIdx.y * 128;
  const int n0 = blockIdx.x * 128;
  const int waveR = (w >> 1) * 64;
  const int waveC = (w & 1) * 64;

  f32x4 acc[4][4];
  #pragma unroll
  for (int i = 0; i < 4; i++)
    #pragma unroll
    for (int j = 0; j < 4; j++) acc[i][j] = (f32x4){0.f, 0.f, 0.f, 0.f};

  for (int kt = 0; kt < DIM / 64; ++kt) {
    const int k0 = kt * 64;
    #pragma unroll
    for (int i = 0; i < 4; ++i) {
      const int rr = w * 32 + i * 8;
      gload_lds16(Xh + (size_t)(m0 + rr + lr) * DIM + k0 + lc * 8, &As[rr * 64]);
      gload_lds16(Wt + (size_t)(n0 + rr + lr) * DIM + k0 + lc * 8, &Bs[rr * 64]);
    }
    __syncthreads();
    #pragma unroll
    for (int ks = 0; ks < 2; ++ks) {
      f16x8 aF[4], bF[4];
      #pragma unroll
      for (int t = 0; t < 4; t++)
        aF[t] = *(const f16x8*)&As[(waveR + t * 16 + l15) * 64 + ks * 32 + quad * 8];
      #pragma unroll
      for (int t = 0; t < 4; t++)
        bF[t] = *(const f16x8*)&Bs[(waveC + t * 16 + l15) * 64 + ks * 32 + quad * 8];
      #pragma unroll
      for (int mt = 0; mt < 4; mt++)
        #pragma unroll
        for (int nt = 0; nt < 4; nt++)
          acc[mt][nt] = __builtin_amdgcn_mfma_f32_16x16x32_f16(aF[mt], bF[nt], acc[mt][nt], 0, 0, 0);
    }
    __syncthreads();
  }
  #pragma unroll
  for (int nt = 0; nt < 4; nt++) {
    const int n = n0 + waveC + nt * 16 + l15;
    const float bias = Bias[n];
    #pragma unroll
    for (int mt = 0; mt < 4; mt++) {
      const int mBase = m0 + waveR + mt * 16 + quad * 4;
      #pragma unroll
      for (int r = 0; r < 4; r++)
        QKV[(size_t)(mBase + r) * NQKV + n] = (_Float16)(acc[mt][nt][r] + bias);
    }
  }
}

// ---------------- kernel 3: RMSNorm(q,k) + RoPE, in place -----------------
// q additionally scaled by QSCALE so flash_attn computes scores directly in
// the log2 domain with no per-score multiply.
__global__ __launch_bounds__(256) void rms_rope(_Float16* __restrict__ QKV,
                                                const float* __restrict__ Cos,
                                                const float* __restrict__ Sin) {
  const int gw   = blockIdx.x * 4 + (threadIdx.x >> 6);
  const int lane = threadIdx.x & 63;
  const int row  = gw / NH;
  const int h    = gw - row * NH;
  const int s    = row & (SEQ - 1);

  _Float16* p = QKV + (size_t)row * NQKV + h * HD;
  float q = (float)p[lane];
  float k = (float)p[DIM + lane];

  float sq = q * q, sk = k * k;
  #pragma unroll
  for (int off = 1; off < 64; off <<= 1) {
    sq += __shfl_xor(sq, off);
    sk += __shfl_xor(sk, off);
  }
  q *= rsqrtf(sq * (1.f / 64.f) + 1e-6f);
  k *= rsqrtf(sk * (1.f / 64.f) + 1e-6f);

  const float c  = Cos[s * HD + lane];
  const float si = Sin[s * HD + lane];
  const float qp = __shfl_xor(q, 1);
  const float kp = __shfl_xor(k, 1);
  float oq, ok;
  if (lane & 1) { oq = q * c + qp * si; ok = k * c + kp * si; }
  else          { oq = q * c - qp * si; ok = k * c - kp * si; }

  p[lane]       = (_Float16)(oq * QSCALE);
  p[DIM + lane] = (_Float16)ok;
}

// ---------------- kernel 4: flash attention, static-max softmax -----------
// BR=128 (32 q-rows per wave), Q in registers, p=exp2(score) with no max
// tracking (score <= 11.54 guaranteed by RMS norm + Cauchy-Schwarz),
// row-sum of rounded P via a ones-column MFMA.
#define LSTR 72
__global__ __launch_bounds__(256) void flash_attn(const _Float16* __restrict__ QKV,
                                                  float* __restrict__ Out) {
  __shared__ __align__(16) _Float16 sm[2 * 64 * LSTR + 4 * 32 * LSTR];
  _Float16* Ks  = sm;
  _Float16* Vts = sm + 64 * LSTR;
  const int w = threadIdx.x >> 6;
  _Float16* Ps = sm + 2 * 64 * LSTR + w * 32 * LSTR;   // wave-private
  const int lane = threadIdx.x & 63;
  const int quad = lane >> 4, l15 = lane & 15;
  const int bh = blockIdx.y;
  const int qt = blockIdx.x;
  const int b  = bh / NH;
  const int h  = bh - b * NH;
  const size_t rowb = (size_t)b * SEQ * NQKV + (size_t)h * HD;  // + s*NQKV per token

  // Q fragments (A-layout) straight from global into registers, kept all loop
  f16x8 qreg[2][2];
  #pragma unroll
  for (int mt = 0; mt < 2; mt++)
    #pragma unroll
    for (int ks = 0; ks < 2; ks++) {
      const int row = qt * 128 + w * 32 + mt * 16 + l15;
      qreg[mt][ks] = *(const f16x8*)(QKV + rowb + (size_t)row * NQKV + ks * 32 + quad * 8);
    }

  // ones B-fragment: column n==0 of the ghost V-tile is all ones
  f16x8 onesF;
  {
    const _Float16 one = (_Float16)(l15 == 0 ? 1.0f : 0.0f);
    #pragma unroll
    for (int j = 0; j < 8; j++) onesF[j] = one;
  }

  f32x4 o[2][4], o4[2];
  #pragma unroll
  for (int mt = 0; mt < 2; mt++) {
    o4[mt] = (f32x4){0.f, 0.f, 0.f, 0.f};
    #pragma unroll
    for (int t = 0; t < 4; t++) o[mt][t] = (f32x4){0.f, 0.f, 0.f, 0.f};
  }

  for (int kt = 0; kt < SEQ / 64; ++kt) {
    __syncthreads();
    // stage K tile (64 keys x 64 d)
    #pragma unroll
    for (int i = 0; i < 2; i++) {
      const int chunk = threadIdx.x + i * 256;
      const int r = chunk >> 3, c0 = (chunk & 7) * 8;
      *(uint4*)&Ks[r * LSTR + c0] =
          *(const uint4*)(QKV + rowb + (size_t)(kt * 64 + r) * NQKV + DIM + c0);
    }
    // stage V tile transposed: Vts[d][key]
    #pragma unroll
    for (int i = 0; i < 2; i++) {
      const int c0 = w * 16 + i * 8;
      union { uint4 v; _Float16 u[8]; } d;
      d.v = *(const uint4*)(QKV + rowb + (size_t)(kt * 64 + lane) * NQKV + 2 * DIM + c0);
      #pragma unroll
      for (int j = 0; j < 8; j++) Vts[(c0 + j) * LSTR + lane] = d.u[j];
    }
    __syncthreads();

    // S = Q K^T : 32 q-rows x 64 keys per wave (scores already in log2 domain)
    f32x4 sacc[2][4];
    #pragma unroll
    for (int mt = 0; mt < 2; mt++)
      #pragma unroll
      for (int t = 0; t < 4; t++) sacc[mt][t] = (f32x4){0.f, 0.f, 0.f, 0.f};
    #pragma unroll
    for (int ks = 0; ks < 2; ks++) {
      f16x8 bF[4];
      #pragma unroll
      for (int t = 0; t < 4; t++)
        bF[t] = *(const f16x8*)&Ks[(t * 16 + l15) * LSTR + ks * 32 + quad * 8];
      #pragma unroll
      for (int mt = 0; mt < 2; mt++)
        #pragma unroll
        for (int t = 0; t < 4; t++)
          sacc[mt][t] = __builtin_amdgcn_mfma_f32_16x16x32_f16(qreg[mt][ks], bF[t], sacc[mt][t], 0, 0, 0);
    }

    // p = exp2(score); write fp16 P to wave-private LDS (no max, no rescale)
    #pragma unroll
    for (int mt = 0; mt < 2; mt++)
      #pragma unroll
      for (int t = 0; t < 4; t++)
        #pragma unroll
        for (int r = 0; r < 4; r++) {
          const _Float16 ph = (_Float16)fexp2(sacc[mt][t][r]);
          Ps[(mt * 16 + quad * 4 + r) * LSTR + t * 16 + l15] = ph;
        }

    // O += P V ; Sigma p (rounded) via ones-column into o4
    #pragma unroll
    for (int ks = 0; ks < 2; ks++) {
      f16x8 pF[2];
      #pragma unroll
      for (int mt = 0; mt < 2; mt++)
        pF[mt] = *(const f16x8*)&Ps[(mt * 16 + l15) * LSTR + ks * 32 + quad * 8];
      #pragma unroll
      for (int t = 0; t < 4; t++) {
        f16x8 vF = *(const f16x8*)&Vts[(t * 16 + l15) * LSTR + ks * 32 + quad * 8];
        #pragma unroll
        for (int mt = 0; mt < 2; mt++)
          o[mt][t] = __builtin_amdgcn_mfma_f32_16x16x32_f16(pF[mt], vF, o[mt][t], 0, 0, 0);
      }
      #pragma unroll
      for (int mt = 0; mt < 2; mt++)
        o4[mt] = __builtin_amdgcn_mfma_f32_16x16x32_f16(pF[mt], onesF, o4[mt], 0, 0, 0);
    }
  }

  // epilogue: lrow = Sigma p lives at lanes l15==0 (col 0 of ones-tile)
  #pragma unroll
  for (int mt = 0; mt < 2; mt++) {
    float lrow[4];
    #pragma unroll
    for (int r = 0; r < 4; r++) lrow[r] = __shfl(o4[mt][r], lane & 48);
    #pragma unroll
    for (int t = 0; t < 4; t++)
      #pragma unroll
      for (int r = 0; r < 4; r++) {
        const int srow = qt * 128 + w * 32 + mt * 16 + quad * 4 + r;
        const int d = t * 16 + l15;
        Out[((size_t)(b * SEQ + srow)) * DIM + h * HD + d] = o[mt][t][r] / lrow[r];
      }
  }
}

// ---------------- launch --------------------------------------------------
extern "C" void kernel_launch(void* const* d_in, const int* in_sizes, int n_in,
                              void* d_out, int out_size, void* d_ws, size_t ws_size,
                              hipStream_t stream) {
  const float* X    = (const float*)d_in[0];
  const float* Cos  = (const float*)d_in[1];
  const float* Sin  = (const float*)d_in[2];
  const float* W    = (const float*)d_in[3];
  const float* Bias = (const float*)d_in[4];
  float* Out = (float*)d_out;

  char* ws = (char*)d_ws;
  _Float16* Xh  = (_Float16*)(ws);                  // 50,331,648 B
  _Float16* Wt  = (_Float16*)(ws + 50331648);       // 14,155,776 B
  _Float16* QKV = (_Float16*)(ws + 64487424);       // 150,994,944 B (end 215,482,368)

  convert_x  <<<dim3(ROWS * DIM / (8 * 256)), 256, 0, stream>>>(X, Xh);
  transpose_w<<<dim3(NQKV / 32, DIM / 32), dim3(32, 8), 0, stream>>>(W, Wt);
  qkv_gemm   <<<dim3(NQKV / 128, ROWS / 128), 256, 0, stream>>>(Xh, Wt, Bias, QKV);
  rms_rope   <<<dim3(ROWS * NH / 4), 256, 0, stream>>>(QKV, Cos, Sin);
  flash_attn <<<dim3(SEQ / 128, BATCH * NH), 256, 0, stream>>>(QKV, Out);
}